// Round 1
// baseline (279.584 us; speedup 1.0000x reference)
//
#include <hip/hip_runtime.h>
#include <hip/hip_bf16.h>

// Binarized-weight 3x3 conv as implicit GEMM:
//   out[n,o,h,w] = sum_{c,kh,kw} sign(W[o,c,kh,kw]) * x[n,c,h+kh-1,w+kw-1]
// GEMM: D[o][p] = sum_k Wmat[o][k] * B[k][p],  k = (kh*3+kw)*128 + c,
// p = n*4096 + h*64 + w.  B is never materialized: for a fixed (kh,kw) the
// K-slice of B is just a shifted window of x in NHWC layout, so the LDS tile
// load is a plain coalesced row copy (padding handled by a zero halo in x_t).

typedef short bf16x8 __attribute__((ext_vector_type(8)));
typedef float f32x4 __attribute__((ext_vector_type(4)));

#define XT_ELEMS (32 * 66 * 66 * 128)
#define XT_BYTES (XT_ELEMS * 2)

__device__ __forceinline__ void glds16(const void* g, const void* l) {
    __builtin_amdgcn_global_load_lds(
        (const __attribute__((address_space(1))) void*)g,
        (__attribute__((address_space(3))) void*)l, 16, 0, 0);
}

// weight OIHW fp32 -> Wmat[o][j][c] = sign(w[o][c][j]) as bf16, j = kh*3+kw
__global__ void prep_w_kernel(const float* __restrict__ w,
                              __hip_bfloat16* __restrict__ wm) {
    int tid = blockIdx.x * 256 + threadIdx.x;   // 294912 total, exact grid
    int o = tid / 1152;
    int r = tid - o * 1152;
    int j = r >> 7;
    int c = r & 127;
    float v = w[o * 1152 + c * 9 + j];
    float s = (v > 0.f) ? 1.f : ((v < 0.f) ? -1.f : 0.f);
    wm[tid] = __float2bfloat16(s);
}

// x NCHW fp32 -> x_t[n][h+1][w+1][c] bf16, 66x66 spatial with zero halo
// (halo zeroed by the memset in kernel_launch).
__global__ void transpose_x_kernel(const float* __restrict__ x,
                                   __hip_bfloat16* __restrict__ xt) {
    int n = blockIdx.x >> 6;
    int h = blockIdx.x & 63;
    const float* xp = x + (size_t)n * 524288 + h * 64;      // xp[c*4096 + w]
    __hip_bfloat16* xo = xt + ((size_t)(n * 66 + h + 1) * 66 + 1) * 128;
    for (int i = threadIdx.x; i < 8192; i += 256) {
        int w = i >> 7;
        int c = i & 127;   // lanes span c: strided reads, L1-resident lines
        xo[w * 128 + c] = __float2bfloat16(xp[c * 4096 + w]);
    }
}

// Block: 128 o  x 128 px (2 image rows of one n). 4 waves, each 64x64.
// K loop: 9 (kh,kw) x 2 chunks of 64 c.  LDS tiles [row][64c] = 128B rows,
// 16B segs XOR-swizzled by (row&7) so ds_read_b128 frag reads are 2-way max.
__global__ __launch_bounds__(256, 2) void gemm_kernel(
    const __hip_bfloat16* __restrict__ xt,
    const __hip_bfloat16* __restrict__ wm,
    float* __restrict__ out) {
    __shared__ short As[128 * 64];   // 16 KB: Wmat tile [o][c]
    __shared__ short Bs[128 * 64];   // 16 KB: x tile   [p][c]

    const int t = threadIdx.x;
    const int lane = t & 63;
    const int wv = t >> 6;
    const int px_blk = blockIdx.x;           // 0..1023
    const int o_blk = blockIdx.y;            // 0..1
    const int n = (px_blk * 128) >> 12;      // one n per block
    const int h0 = ((px_blk * 128) & 4095) >> 6;  // even; rows h0, h0+1

    const int wo = (wv & 1) * 64;            // wave origin in o
    const int wp = (wv >> 1) * 64;           // wave origin in px
    const int l15 = lane & 15;
    const int quad = lane >> 4;
    const int srow = lane >> 3;              // staging: row within 8-row group
    const int sseg = lane & 7;               // staging: physical 16B seg

    const short* wmS = (const short*)wm + (o_blk * 128) * 1152;
    const short* xtS = (const short*)xt;

    f32x4 acc[4][4] = {};

    for (int j = 0; j < 9; ++j) {
        const int kh = j / 3;
        const int kw = j - kh * 3;
        for (int cc = 0; cc < 128; cc += 64) {
            // --- stage A (weights): wave wv covers rows [wv*32, wv*32+32)
#pragma unroll
            for (int i = 0; i < 4; ++i) {
                const int r0 = wv * 32 + i * 8;
                const int r = r0 + srow;
                const int segl = sseg ^ (r & 7);   // source-side swizzle
                glds16(wmS + r * 1152 + j * 128 + cc + segl * 8,
                       As + r0 * 64);
            }
            // --- stage B (x window): row p -> x_t[n][h0+(p>>6)+kh-1][(p&63)+kw-1][c]
#pragma unroll
            for (int i = 0; i < 4; ++i) {
                const int r0 = wv * 32 + i * 8;
                const int p = r0 + srow;
                const int hh = h0 + (p >> 6) + kh;   // (+1 halo offset folded in)
                const int ww = (p & 63) + kw;
                const int segl = sseg ^ (p & 7);
                glds16(xtS + ((size_t)(n * 66 + hh) * 66 + ww) * 128 + cc + segl * 8,
                       Bs + r0 * 64);
            }
            __syncthreads();
#pragma unroll
            for (int kf = 0; kf < 2; ++kf) {
                bf16x8 a[4], b[4];
#pragma unroll
                for (int i = 0; i < 4; ++i) {
                    const int o = wo + i * 16 + l15;
                    const int seg = (kf * 4 + quad) ^ (o & 7);
                    a[i] = *(const bf16x8*)(As + o * 64 + seg * 8);
                }
#pragma unroll
                for (int i = 0; i < 4; ++i) {
                    const int p = wp + i * 16 + l15;
                    const int seg = (kf * 4 + quad) ^ (p & 7);
                    b[i] = *(const bf16x8*)(Bs + p * 64 + seg * 8);
                }
#pragma unroll
                for (int i = 0; i < 4; ++i)
#pragma unroll
                    for (int jj = 0; jj < 4; ++jj)
                        acc[i][jj] = __builtin_amdgcn_mfma_f32_16x16x32_bf16(
                            a[i], b[jj], acc[i][jj], 0, 0, 0);
            }
            __syncthreads();
        }
    }

    // Epilogue: C/D layout col=lane&15 (px), row=quad*4+reg (o)
    const int Pbase = px_blk * 128 + wp;
#pragma unroll
    for (int i = 0; i < 4; ++i) {
#pragma unroll
        for (int jj = 0; jj < 4; ++jj) {
            const int P = Pbase + jj * 16 + l15;
            const int hw = P & 4095;
            float* op = out + (size_t)n * 1048576 + hw;
#pragma unroll
            for (int r = 0; r < 4; ++r) {
                const int o = o_blk * 128 + wo + i * 16 + quad * 4 + r;
                op[(size_t)o * 4096] = acc[i][jj][r];
            }
        }
    }
}

extern "C" void kernel_launch(void* const* d_in, const int* in_sizes, int n_in,
                              void* d_out, int out_size, void* d_ws, size_t ws_size,
                              hipStream_t stream) {
    const float* x = (const float*)d_in[0];
    const float* w = (const float*)d_in[1];
    float* out = (float*)d_out;
    __hip_bfloat16* xt = (__hip_bfloat16*)d_ws;
    __hip_bfloat16* wm = (__hip_bfloat16*)((char*)d_ws + XT_BYTES);

    // zero halo (and interior, overwritten) — d_ws is re-poisoned every call
    hipMemsetAsync(d_ws, 0, XT_BYTES, stream);
    prep_w_kernel<<<1152, 256, 0, stream>>>(w, wm);
    transpose_x_kernel<<<2048, 256, 0, stream>>>(x, xt);
    gemm_kernel<<<dim3(1024, 2), 256, 0, stream>>>(xt, wm, out);
}

// Round 2
// 248.395 us; speedup vs baseline: 1.1256x; 1.1256x over previous
//
#include <hip/hip_runtime.h>
#include <hip/hip_bf16.h>

// Binarized-weight 3x3 conv as implicit GEMM:
//   out[n,o,h,w] = sum_{c,kh,kw} sign(W[o,c,kh,kw]) * x[n,c,h+kh-1,w+kw-1]
// GEMM: D[o][p] = sum_k Wmat[o][k] * B[k][p],  k = (kh*3+kw)*128 + c.
// B never materialized: for fixed (kh,kw) the K-slice of B is a shifted
// window of x in NHWC (zero halo handles padding). R2: B staged as a
// 4-row x 66-col window per (cc,kh), reused across kw; 64o x 128px wave
// tiles (12 ds_read_b128 : 32 MFMA per kf).

typedef short bf16x8 __attribute__((ext_vector_type(8)));
typedef float f32x4 __attribute__((ext_vector_type(4)));

#define XT_ELEMS (32 * 66 * 66 * 128)
#define XT_BYTES (XT_ELEMS * 2)

__device__ __forceinline__ void glds16(const void* g, const void* l) {
    __builtin_amdgcn_global_load_lds(
        (const __attribute__((address_space(1))) void*)g,
        (__attribute__((address_space(3))) void*)l, 16, 0, 0);
}

// weight OIHW fp32 -> Wmat[o][j][c] = sign(w[o][c][j]) as bf16, j = kh*3+kw
__global__ void prep_w_kernel(const float* __restrict__ w,
                              __hip_bfloat16* __restrict__ wm) {
    int tid = blockIdx.x * 256 + threadIdx.x;   // 294912 total, exact grid
    int o = tid / 1152;
    int r = tid - o * 1152;
    int j = r >> 7;
    int c = r & 127;
    float v = w[o * 1152 + c * 9 + j];
    float s = (v > 0.f) ? 1.f : ((v < 0.f) ? -1.f : 0.f);
    wm[tid] = __float2bfloat16(s);
}

// x NCHW fp32 -> x_t[n][h+1][w+1][c] bf16 (66x66 spatial, zero halo).
// Coalesced both ways via LDS bounce; halo zeroing folded in (no memset).
__global__ void transpose_x_kernel(const float* __restrict__ x,
                                   __hip_bfloat16* __restrict__ xt) {
    __shared__ short tl[64 * 130];   // stride 130: +65 banks/row -> 2-way max
    const int t = threadIdx.x;
    const int n = blockIdx.x >> 6;
    const int h = blockIdx.x & 63;
    const float* xp = x + (size_t)n * 524288 + h * 64;
    // phase 1: lanes span w -> 256 B contiguous per wave-load
    for (int i = t; i < 8192; i += 256) {
        int w = i & 63, c = i >> 6;
        tl[w * 130 + c] = (short)__bfloat16_as_ushort(__float2bfloat16(xp[c * 4096 + w]));
    }
    // halo zeroing (disjoint addresses; no barrier needed vs phase 2)
    uint* xtn = (uint*)(xt + (size_t)n * 66 * 66 * 128);
    {
        int row = h + 1;
        if (t < 64)       xtn[(row * 66 + 0) * 64 + t] = 0u;        // col 0
        else if (t < 128) xtn[(row * 66 + 65) * 64 + (t - 64)] = 0u; // col 65
    }
    if (h == 0)  for (int i = t; i < 66 * 64; i += 256) xtn[i] = 0u;                  // row 0
    if (h == 63) for (int i = t; i < 66 * 64; i += 256) xtn[65 * 66 * 64 + i] = 0u;   // row 65
    __syncthreads();
    // phase 2: lanes span c (uint = 2 shorts) -> 256 B contiguous stores
    uint* xo = (uint*)(xt + ((size_t)(n * 66 + h + 1) * 66 + 1) * 128);
    for (int i = t; i < 4096; i += 256) {
        int c2 = i & 63;
        int w = i >> 6;
        xo[w * 64 + c2] = *(const uint*)(tl + w * 130 + c2 * 2);
    }
}

// Block: 128 o x 256 px (4 out rows of one n). 4 waves, each 64o x 128px.
// LDS: As[o][64c] 16 KB (restaged per j), Bw 4x66-cell window 33 KB
// (restaged per (cc,kh), reused across kw). 16B segs XOR-swizzled by
// (row&7)/(cell&7) so all ds_read_b128 are 2-way max (measured 0 conflicts).
__global__ __launch_bounds__(256, 2) void gemm_kernel(
    const __hip_bfloat16* __restrict__ xt,
    const __hip_bfloat16* __restrict__ wm,
    float* __restrict__ out) {
    __shared__ short As[128 * 64];    // 16384 B
    __shared__ short Bw[2112 * 8];    // 33792 B: 264 cells x 8 segs x 16 B

    const int t = threadIdx.x;
    const int lane = t & 63;
    const int wv = t >> 6;
    const int px_blk = blockIdx.x;    // 0..511
    const int o_blk = blockIdx.y;     // 0..1
    const int n = px_blk >> 4;
    const int h0 = (px_blk & 15) * 4;

    const int wo = (wv & 1) * 64;     // wave origin in o
    const int wp = (wv >> 1) * 128;   // wave origin in px
    const int wpr = wp >> 6;          // wave px-row origin (0 or 2)
    const int l15 = lane & 15;
    const int quad = lane >> 4;
    const int srow = lane >> 3;
    const int sseg = lane & 7;

    const short* wmS = (const short*)wm + (o_blk * 128) * 1152;
    const short* xtS = (const short*)xt;

    f32x4 acc[4][8] = {};   // [o frag][px frag]

    for (int cc = 0; cc < 128; cc += 64) {
        for (int kh = 0; kh < 3; ++kh) {
            // --- stage B window: rows (h0+kh .. h0+kh+3) x 66 cols x 64 c
            // 2112 segs = 33 full wave-issues; dest contiguous per issue.
            const short* xw = xtS + ((size_t)(n * 66 + h0 + kh) * 66) * 128;
#pragma unroll
            for (int i = 0; i < 9; ++i) {
                int bidx = i * 4 + wv;
                if (bidx < 33) {
                    int l = bidx * 64 + lane;
                    int cell = l >> 3;
                    int q = l & 7;
                    int s = q ^ (cell & 7);
                    glds16(xw + cell * 128 + cc + s * 8, Bw + bidx * 512);
                }
            }
            for (int kw = 0; kw < 3; ++kw) {
                const int j = kh * 3 + kw;
                // --- stage A chunk: 128 o x 64 c
#pragma unroll
                for (int i = 0; i < 4; ++i) {
                    int r0 = wv * 32 + i * 8;
                    int r = r0 + srow;
                    int segl = sseg ^ (r & 7);
                    glds16(wmS + r * 1152 + j * 128 + cc + segl * 8,
                           As + r0 * 64);
                }
                __syncthreads();
#pragma unroll
                for (int kf = 0; kf < 2; ++kf) {
                    bf16x8 a[4], b[8];
#pragma unroll
                    for (int i = 0; i < 4; ++i) {
                        int o = wo + i * 16 + l15;
                        int seg = (kf * 4 + quad) ^ (o & 7);
                        a[i] = *(const bf16x8*)(As + o * 64 + seg * 8);
                    }
#pragma unroll
                    for (int i = 0; i < 8; ++i) {
                        int cell = (wpr + (i >> 2)) * 66 + (i & 3) * 16 + l15 + kw;
                        int seg = (kf * 4 + quad) ^ (cell & 7);
                        b[i] = *(const bf16x8*)(Bw + cell * 64 + seg * 8);
                    }
#pragma unroll
                    for (int i = 0; i < 4; ++i)
#pragma unroll
                        for (int jj = 0; jj < 8; ++jj)
                            acc[i][jj] = __builtin_amdgcn_mfma_f32_16x16x32_bf16(
                                a[i], b[jj], acc[i][jj], 0, 0, 0);
                }
                __syncthreads();
            }
        }
    }

    // Epilogue: C/D layout col=lane&15 (px), row=quad*4+reg (o)
    const int Pbase = px_blk * 256 + wp;
#pragma unroll
    for (int i = 0; i < 4; ++i) {
#pragma unroll
        for (int jj = 0; jj < 8; ++jj) {
            const int P = Pbase + jj * 16 + l15;
            const int hw = P & 4095;
            float* op = out + (size_t)n * 1048576 + hw;
#pragma unroll
            for (int r = 0; r < 4; ++r) {
                const int o = o_blk * 128 + wo + i * 16 + quad * 4 + r;
                op[(size_t)o * 4096] = acc[i][jj][r];
            }
        }
    }
}

extern "C" void kernel_launch(void* const* d_in, const int* in_sizes, int n_in,
                              void* d_out, int out_size, void* d_ws, size_t ws_size,
                              hipStream_t stream) {
    const float* x = (const float*)d_in[0];
    const float* w = (const float*)d_in[1];
    float* out = (float*)d_out;
    __hip_bfloat16* xt = (__hip_bfloat16*)d_ws;
    __hip_bfloat16* wm = (__hip_bfloat16*)((char*)d_ws + XT_BYTES);

    prep_w_kernel<<<1152, 256, 0, stream>>>(w, wm);
    transpose_x_kernel<<<2048, 256, 0, stream>>>(x, xt);
    gemm_kernel<<<dim3(512, 2), 256, 0, stream>>>(xt, wm, out);
}